// Round 19
// baseline (870.986 us; speedup 1.0000x reference)
//
#include <hip/hip_runtime.h>
#include <stdint.h>

typedef unsigned short u16t;
typedef unsigned int   u32t;
typedef unsigned long long u64t;
typedef __attribute__((ext_vector_type(4))) float f32x4;
typedef __attribute__((ext_vector_type(8))) short s16x8;
typedef __attribute__((ext_vector_type(4))) u32t u32x4;

#define NB 4
#define NS 2048
#define ND 1024
#define NH 16
#define NBH 64
#define NTOK 8192
#define TOPK 204
#define KSCALE2 738.6598609351492f   /* 4 * 1024*log2(e)/8 — 4x finer keys */

__device__ __forceinline__ u16t f2bf(float f){
  u32t u = __builtin_bit_cast(u32t, f);
  u32t r = (u + 0x7FFFu + ((u >> 16) & 1u)) >> 16;
  return (u16t)r;
}
__device__ __forceinline__ float bf2f(u16t h){
  u32t u = ((u32t)h) << 16;
  return __builtin_bit_cast(float, u);
}
__device__ __forceinline__ f32x4 mfma16(s16x8 a, s16x8 b, f32x4 c){
  return __builtin_amdgcn_mfma_f32_16x16x32_bf16(a, b, c, 0, 0, 0);
}
__device__ __forceinline__ u32t pk_bf16(float a, float b){
  u32t r;
  asm volatile("v_cvt_pk_bf16_f32 %0, %1, %2" : "=v"(r) : "v"(a), "v"(b));
  return r;
}
__device__ __forceinline__ u32t mkkey(float s){
  float kf = fmaf(s, KSCALE2, 32768.5f);  // +0.5: truncation = round-half-up (monotone)
  kf = fminf(fmaxf(kf, 0.0f), 65535.0f);  // |s_dot| <= 44.4 (11 sigma) before clamp
  return (u32t)kf;
}
__device__ __forceinline__ float exp2_fast(float x){
#if __has_builtin(__builtin_amdgcn_exp2f)
  return __builtin_amdgcn_exp2f(x);
#else
  return exp2f(x);
#endif
}

#define SWZ(r) (((r) & 7) << 4)

// ---------------- fused prep: split x, split Wqkv, cvt Wo (range-dispatched) ----------------
#define N1 (NTOK*ND/4)
#define N2 (3072*1024/4)
#define N3 (1024*1024/4)
__global__ __launch_bounds__(256) void prep_kernel(
    const float* __restrict__ x,    u16t* __restrict__ xhi, u16t* __restrict__ xlo,
    const float* __restrict__ Wq,   u16t* __restrict__ wqh, u16t* __restrict__ wql,
    const float* __restrict__ Wo,   u16t* __restrict__ wob)
{
  int i = blockIdx.x * 256 + threadIdx.x;
  const float* src; u16t* hi; u16t* lo; int idx; int dolo;
  if (i < N1){ src = x; hi = xhi; lo = xlo; idx = i; dolo = 1; }
  else if (i < N1 + N2){ src = Wq; hi = wqh; lo = wql; idx = i - N1; dolo = 1; }
  else if (i < N1 + N2 + N3){ src = Wo; hi = wob; lo = 0; idx = i - N1 - N2; dolo = 0; }
  else return;
  float4 v = ((const float4*)src)[idx];
  float a0=v.x, a1=v.y, a2=v.z, a3=v.w;
  u16t h0=f2bf(a0), h1=f2bf(a1), h2=f2bf(a2), h3=f2bf(a3);
  ((u64t*)hi)[idx] = (u64t)h0 | ((u64t)h1<<16) | ((u64t)h2<<32) | ((u64t)h3<<48);
  if (dolo){
    u16t l0=f2bf(a0-bf2f(h0)), l1=f2bf(a1-bf2f(h1)), l2=f2bf(a2-bf2f(h2)), l3=f2bf(a3-bf2f(h3));
    ((u64t*)lo)[idx] = (u64t)l0 | ((u64t)l1<<16) | ((u64t)l2<<32) | ((u64t)l3<<48);
  }
}

// ---------------- QKV GEMM: C[8192,3072] = (xh+xl)(Wh+Wl)^T + b, split 3-pass ----------------
// f32-grade accuracy; epilogue stores q,k as SINGLE bf16 and v transposed bf16.
__global__ __launch_bounds__(256) void qkv_gemm_kernel(
    const u16t* __restrict__ Ah, const u16t* __restrict__ Al,
    const u16t* __restrict__ Bh, const u16t* __restrict__ Bl,
    const float* __restrict__ bias,
    u16t* __restrict__ qb, u16t* __restrict__ kb, u16t* __restrict__ vt)
{
  __shared__ u16t lds[4*4096];
  const int tid = threadIdx.x;
  const int l = tid & 63, w = tid >> 6;
  const int wr = w >> 1, wc = w & 1;
  const int mt = blockIdx.y, nt = blockIdx.x;
  f32x4 acc[4][4] = {};
  for (int ks = 0; ks < 32; ++ks){
    __syncthreads();
    #pragma unroll
    for (int p = 0; p < 4; ++p){
      const u16t* src = (p==0) ? Ah : (p==1) ? Al : (p==2) ? Bh : Bl;
      int rb = ((p < 2) ? mt : nt) * 128;
      #pragma unroll
      for (int ii = 0; ii < 2; ++ii){
        int c = tid + ii*256;
        int row = c >> 2, kc = c & 3;
        s16x8 v = *(const s16x8*)(src + (size_t)(rb + row)*1024 + ks*32 + kc*8);
        *(s16x8*)((char*)lds + p*8192 + ((row*64 + kc*16) ^ SWZ(row))) = v;
      }
    }
    __syncthreads();
    s16x8 afh[4], afl[4], bfh[4], bfl[4];
    const int kbs = (l >> 4) * 16;
    #pragma unroll
    for (int i = 0; i < 4; ++i){
      int row = wr*64 + i*16 + (l & 15);
      int off = (row*64 + kbs) ^ SWZ(row);
      afh[i] = *(const s16x8*)((char*)lds + off);
      afl[i] = *(const s16x8*)((char*)lds + 8192 + off);
    }
    #pragma unroll
    for (int j = 0; j < 4; ++j){
      int row = wc*64 + j*16 + (l & 15);
      int off = (row*64 + kbs) ^ SWZ(row);
      bfh[j] = *(const s16x8*)((char*)lds + 16384 + off);
      bfl[j] = *(const s16x8*)((char*)lds + 24576 + off);
    }
    #pragma unroll
    for (int i = 0; i < 4; ++i)
      #pragma unroll
      for (int j = 0; j < 4; ++j){
        acc[i][j] = mfma16(afh[i], bfh[j], acc[i][j]);
        acc[i][j] = mfma16(afh[i], bfl[j], acc[i][j]);
        acc[i][j] = mfma16(afl[i], bfh[j], acc[i][j]);
      }
  }
  #pragma unroll
  for (int j = 0; j < 4; ++j){
    int col = nt*128 + wc*64 + j*16 + (l & 15);
    float bv = bias[col];
    #pragma unroll
    for (int i = 0; i < 4; ++i){
      int tok0 = mt*128 + wr*64 + i*16 + (l >> 4)*4;
      int b = tok0 >> 11;
      int s0 = tok0 & 2047;
      if (col < 1024){
        int h = col >> 6, d = col & 63;
        u16t* dst = qb + ((size_t)(b*NH + h)*NS + s0)*64 + d;
        #pragma unroll
        for (int r = 0; r < 4; ++r) dst[(size_t)r*64] = f2bf(acc[i][j][r] + bv);
      } else if (col < 2048){
        int ch = col - 1024; int h = ch >> 6, d = ch & 63;
        u16t* dst = kb + ((size_t)(b*NH + h)*NS + s0)*64 + d;
        #pragma unroll
        for (int r = 0; r < 4; ++r) dst[(size_t)r*64] = f2bf(acc[i][j][r] + bv);
      } else {
        int ch = col - 2048; int h = ch >> 6, d = ch & 63;
        u32t p0 = (u32t)f2bf(acc[i][j][0] + bv) | ((u32t)f2bf(acc[i][j][1] + bv) << 16);
        u32t p1 = (u32t)f2bf(acc[i][j][2] + bv) | ((u32t)f2bf(acc[i][j][3] + bv) << 16);
        u64t pk = (u64t)p0 | ((u64t)p1 << 32);
        *(u64t*)(vt + ((size_t)(b*NH + h)*64 + d)*NS + s0) = pk; // 4 consecutive s packed
      }
    }
  }
}

// ---------------- out GEMM: Y[8192,1024] = A(bf16) @ Wo^T(bf16) + bo, f32 out ----------------
__global__ __launch_bounds__(256) void out_gemm_kernel(
    const u16t* __restrict__ A, const u16t* __restrict__ Bt,
    const float* __restrict__ bias, float* __restrict__ Y)
{
  __shared__ u16t lds[2*4096];
  const int tid = threadIdx.x;
  const int l = tid & 63, w = tid >> 6;
  const int wr = w >> 1, wc = w & 1;
  const int mt = blockIdx.y, nt = blockIdx.x;
  f32x4 acc[4][4] = {};
  for (int ks = 0; ks < 32; ++ks){
    __syncthreads();
    #pragma unroll
    for (int p = 0; p < 2; ++p){
      const u16t* src = p ? Bt : A;
      int rb = (p ? nt : mt) * 128;
      #pragma unroll
      for (int ii = 0; ii < 2; ++ii){
        int c = tid + ii*256;
        int row = c >> 2, kc = c & 3;
        s16x8 v = *(const s16x8*)(src + (size_t)(rb + row)*1024 + ks*32 + kc*8);
        *(s16x8*)((char*)lds + p*8192 + ((row*64 + kc*16) ^ SWZ(row))) = v;
      }
    }
    __syncthreads();
    s16x8 af[4], bf[4];
    const int kbs = (l >> 4) * 16;
    #pragma unroll
    for (int i = 0; i < 4; ++i){
      int row = wr*64 + i*16 + (l & 15);
      af[i] = *(const s16x8*)((char*)lds + ((row*64 + kbs) ^ SWZ(row)));
    }
    #pragma unroll
    for (int j = 0; j < 4; ++j){
      int row = wc*64 + j*16 + (l & 15);
      bf[j] = *(const s16x8*)((char*)lds + 8192 + ((row*64 + kbs) ^ SWZ(row)));
    }
    #pragma unroll
    for (int i = 0; i < 4; ++i)
      #pragma unroll
      for (int j = 0; j < 4; ++j)
        acc[i][j] = mfma16(af[i], bf[j], acc[i][j]);
  }
  #pragma unroll
  for (int j = 0; j < 4; ++j){
    int col = nt*128 + wc*64 + j*16 + (l & 15);
    float bv = bias[col];
    #pragma unroll
    for (int i = 0; i < 4; ++i){
      int tok0 = mt*128 + wr*64 + i*16 + (l >> 4)*4;
      float* dst = Y + (size_t)tok0*1024 + col;
      #pragma unroll
      for (int r = 0; r < 4; ++r) dst[(size_t)r*1024] = acc[i][j][r] + bv;
    }
  }
}

// ---------------- fused sparse attention: 1 WG = (bh, 16 q-rows), 2 blocks/CU ----------------
// Phase 2 software pipeline: all 4 rows' keys register-resident with STATIC names;
// order = bisect(pair0) -> bisect(pair1) [hidden under] weights(pair0) -> weights(pair1).
// No runtime-indexed register operands anywhere (R17's cndmask bug avoided).
__global__ __launch_bounds__(256, 2) void attn_fused_kernel(
    const u16t* __restrict__ qb, const u16t* __restrict__ kb,
    const u16t* __restrict__ vtg, u16t* __restrict__ aout)
{
  extern __shared__ char smem[];   // 65536 keys/weights + 64 zinv
  float* zlds = (float*)(smem + 65536);
  const int tid = threadIdx.x;
  const int l = tid & 63, w = tid >> 6;
  int lid = ((blockIdx.x & 7) << 10) | (blockIdx.x >> 3); // XCD-chunked swizzle (8192%8==0)
  const int bh = lid >> 7, qt = lid & 127;
  const int qrow = l & 15;
  const size_t kbase = (size_t)bh*NS*64 + (l >> 4)*8;

  // Phase 0: Q fragments (B operand): row = qrow, d-slice = c*32 + (l>>4)*8
  s16x8 qh[2];
  {
    const u16t* qp = qb + ((size_t)bh*NS + qt*16 + qrow)*64 + (l >> 4)*8;
    qh[0] = *(const s16x8*)(qp);
    qh[1] = *(const s16x8*)(qp + 32);
  }

  // Phase 1: keys. Wave w handles toks g*64 + w*16 .. +15, g = 0..31; depth-2 prefetch.
  {
    s16x8 Ah0, Ah1, Bh0, Bh1;
    {
      size_t a = kbase + (size_t)(w*16 + qrow)*64;
      Ah0 = *(const s16x8*)(kb + a);  Ah1 = *(const s16x8*)(kb + a + 32);
      size_t b = kbase + (size_t)(64 + w*16 + qrow)*64;
      Bh0 = *(const s16x8*)(kb + b);  Bh1 = *(const s16x8*)(kb + b + 32);
    }
    #pragma unroll 1
    for (int g = 0; g < 32; g += 2){
      // even iter: consume A (g), refill A with g+2
      {
        __builtin_amdgcn_s_setprio(1);
        f32x4 aA = {}, aB = {};
        aA = mfma16(Ah0, qh[0], aA);
        aB = mfma16(Ah1, qh[1], aB);
        __builtin_amdgcn_s_setprio(0);
        if (g + 2 < 32){
          size_t a = kbase + (size_t)((g+2)*64 + w*16 + qrow)*64;
          Ah0 = *(const s16x8*)(kb + a);  Ah1 = *(const s16x8*)(kb + a + 32);
        }
        f32x4 acc = aA + aB;
        int t0 = g*64 + w*16 + (l >> 4)*4;
        u32t k0 = mkkey(acc[0]), k1 = mkkey(acc[1]);
        u32t k2 = mkkey(acc[2]), k3 = mkkey(acc[3]);
        u64t pk = (u64t)(k0 | (k1 << 16)) | ((u64t)(k2 | (k3 << 16)) << 32);
        *(u64t*)(smem + ((qrow*4096 + t0*2) ^ SWZ(qrow))) = pk;
      }
      // odd iter: consume B (g+1), refill B with g+3
      {
        __builtin_amdgcn_s_setprio(1);
        f32x4 aA = {}, aB = {};
        aA = mfma16(Bh0, qh[0], aA);
        aB = mfma16(Bh1, qh[1], aB);
        __builtin_amdgcn_s_setprio(0);
        if (g + 3 < 32){
          size_t b = kbase + (size_t)((g+3)*64 + w*16 + qrow)*64;
          Bh0 = *(const s16x8*)(kb + b);  Bh1 = *(const s16x8*)(kb + b + 32);
        }
        f32x4 acc = aA + aB;
        int t0 = (g+1)*64 + w*16 + (l >> 4)*4;
        u32t k0 = mkkey(acc[0]), k1 = mkkey(acc[1]);
        u32t k2 = mkkey(acc[2]), k3 = mkkey(acc[3]);
        u64t pk = (u64t)(k0 | (k1 << 16)) | ((u64t)(k2 | (k3 << 16)) << 32);
        *(u64t*)(smem + ((qrow*4096 + t0*2) ^ SWZ(qrow))) = pk;
      }
    }
  }
  __syncthreads();

  // Phase 2: software-pipelined across the two row pairs (static register names only).
  {
    const int r0 = w*4, r1 = r0+1, r2 = r0+2, r3 = r0+3;
    const int rb0 = r0*4096, rs0 = SWZ(r0);
    const int rb1 = r1*4096, rs1 = SWZ(r1);
    const int rb2 = r2*4096, rs2 = SWZ(r2);
    const int rb3 = r3*4096, rs3 = SWZ(r3);
    u32t ka[32], kc[32], ke[32], kg[32];
    #pragma unroll
    for (int i = 0; i < 4; ++i){
      u32x4 v0 = *(const u32x4*)(smem + ((rb0 + i*1024 + l*16) ^ rs0));
      u32x4 v1 = *(const u32x4*)(smem + ((rb1 + i*1024 + l*16) ^ rs1));
      u32x4 v2 = *(const u32x4*)(smem + ((rb2 + i*1024 + l*16) ^ rs2));
      u32x4 v3 = *(const u32x4*)(smem + ((rb3 + i*1024 + l*16) ^ rs3));
      #pragma unroll
      for (int j = 0; j < 4; ++j){
        ka[(i*4+j)*2] = v0[j] & 0xFFFFu;  ka[(i*4+j)*2+1] = v0[j] >> 16;
        kc[(i*4+j)*2] = v1[j] & 0xFFFFu;  kc[(i*4+j)*2+1] = v1[j] >> 16;
        ke[(i*4+j)*2] = v2[j] & 0xFFFFu;  ke[(i*4+j)*2+1] = v2[j] >> 16;
        kg[(i*4+j)*2] = v3[j] & 0xFFFFu;  kg[(i*4+j)*2+1] = v3[j] >> 16;
      }
    }
    // Step 1: dual bisection for pair0 (rows r0,r1)
    u32t lo0 = 0u, hi0 = 65535u, lo1 = 0u, hi1 = 65535u;
    #pragma unroll 1
    for (int it = 0; it < 16; ++it){
      u32t m0 = (lo0 + hi0 + 1u) >> 1;
      u32t m1 = (lo1 + hi1 + 1u) >> 1;
      u32t c0 = 0, c1 = 0;
      #pragma unroll
      for (int i = 0; i < 32; ++i){
        c0 += (u32t)__popcll(__ballot(ka[i] >= m0));
        c1 += (u32t)__popcll(__ballot(kc[i] >= m1));
      }
      if (c0 >= (u32t)TOPK) lo0 = m0; else hi0 = m0 - 1u;
      if (c1 >= (u32t)TOPK) lo1 = m1; else hi1 = m1 - 1u;
    }
    const u32t kbt0 = lo0, kbt1 = lo1;

    // Step 2: dual bisection for pair1 (rows r2,r3) — UNROLLED so the scheduler can
    // interleave its serial chain with Step 3's independent weight-pass issue stream.
    u32t lo2 = 0u, hi2 = 65535u, lo3 = 0u, hi3 = 65535u;
    #pragma unroll
    for (int it = 0; it < 16; ++it){
      u32t m2 = (lo2 + hi2 + 1u) >> 1;
      u32t m3 = (lo3 + hi3 + 1u) >> 1;
      u32t c2 = 0, c3 = 0;
      #pragma unroll
      for (int i = 0; i < 32; ++i){
        c2 += (u32t)__popcll(__ballot(ke[i] >= m2));
        c3 += (u32t)__popcll(__ballot(kg[i] >= m3));
      }
      if (c2 >= (u32t)TOPK) lo2 = m2; else hi2 = m2 - 1u;
      if (c3 >= (u32t)TOPK) lo3 = m3; else hi3 = m3 - 1u;
    }
    const u32t kbt2 = lo2, kbt3 = lo3;

    // Step 3: weights pair0 (independent of Step 2 — interleaves with it)
    {
      float zsA = 0.0f, zsB = 0.0f;
      #pragma unroll
      for (int i = 0; i < 4; ++i){
        u32x4 oa, ob;
        #pragma unroll
        for (int j = 0; j < 4; ++j){
          int e = (i*4+j)*2;
          float eA0 = exp2_fast(fmaf((float)ka[e],   2.44140625e-4f, -8.0f));
          float eA1 = exp2_fast(fmaf((float)ka[e+1], 2.44140625e-4f, -8.0f));
          float eB0 = exp2_fast(fmaf((float)kc[e],   2.44140625e-4f, -8.0f));
          float eB1 = exp2_fast(fmaf((float)kc[e+1], 2.44140625e-4f, -8.0f));
          float wA0 = (ka[e]   >= kbt0) ? eA0 : 1.0f;
          float wA1 = (ka[e+1] >= kbt0) ? eA1 : 1.0f;
          float wB0 = (kc[e]   >= kbt1) ? eB0 : 1.0f;
          float wB1 = (kc[e+1] >= kbt1) ? eB1 : 1.0f;
          zsA += wA0 + wA1;
          zsB += wB0 + wB1;
          oa[j] = pk_bf16(wA0, wA1);
          ob[j] = pk_bf16(wB0, wB1);
        }
        *(u32x4*)(smem + ((rb0 + i*1024 + l*16) ^ rs0)) = oa;
        *(u32x4*)(smem + ((rb1 + i*1024 + l*16) ^ rs1)) = ob;
      }
      #pragma unroll
      for (int o = 32; o; o >>= 1){
        zsA += __shfl_xor(zsA, o);
        zsB += __shfl_xor(zsB, o);
      }
      if (l == 0){
        zlds[r0] = 1.0f / (zsA + 1e-9f);
        zlds[r1] = 1.0f / (zsB + 1e-9f);
      }
    }
    // Step 4: weights pair1
    {
      float zsA = 0.0f, zsB = 0.0f;
      #pragma unroll
      for (int i = 0; i < 4; ++i){
        u32x4 oa, ob;
        #pragma unroll
        for (int j = 0; j < 4; ++j){
          int e = (i*4+j)*2;
          float eA0 = exp2_fast(fmaf((float)ke[e],   2.44140625e-4f, -8.0f));
          float eA1 = exp2_fast(fmaf((float)ke[e+1], 2.44140625e-4f, -8.0f));
          float eB0 = exp2_fast(fmaf((float)kg[e],   2.44140625e-4f, -8.0f));
          float eB1 = exp2_fast(fmaf((float)kg[e+1], 2.44140625e-4f, -8.0f));
          float wA0 = (ke[e]   >= kbt2) ? eA0 : 1.0f;
          float wA1 = (ke[e+1] >= kbt2) ? eA1 : 1.0f;
          float wB0 = (kg[e]   >= kbt3) ? eB0 : 1.0f;
          float wB1 = (kg[e+1] >= kbt3) ? eB1 : 1.0f;
          zsA += wA0 + wA1;
          zsB += wB0 + wB1;
          oa[j] = pk_bf16(wA0, wA1);
          ob[j] = pk_bf16(wB0, wB1);
        }
        *(u32x4*)(smem + ((rb2 + i*1024 + l*16) ^ rs2)) = oa;
        *(u32x4*)(smem + ((rb3 + i*1024 + l*16) ^ rs3)) = ob;
      }
      #pragma unroll
      for (int o = 32; o; o >>= 1){
        zsA += __shfl_xor(zsA, o);
        zsB += __shfl_xor(zsB, o);
      }
      if (l == 0){
        zlds[r2] = 1.0f / (zsA + 1e-9f);
        zlds[r3] = 1.0f / (zsB + 1e-9f);
      }
    }
  }
  __syncthreads();

  // Phase 3: PV via mfma(V^T, W): C[d][qrow]. Wave w owns d-block w*16..+15; depth-2 prefetch.
  f32x4 pA = {}, pB = {};
  {
    const u16t* vp = vtg + ((size_t)bh*64 + w*16 + qrow)*NS + (l >> 4)*8;
    s16x8 Va0 = *(const s16x8*)(vp);        s16x8 Va1 = *(const s16x8*)(vp + 32);
    s16x8 Vb0 = *(const s16x8*)(vp + 64);   s16x8 Vb1 = *(const s16x8*)(vp + 96);
    #pragma unroll 1
    for (int kt = 0; kt < 32; kt += 2){
      {
        int tb = (kt*64 + (l >> 4)*8)*2;
        s16x8 w0 = *(const s16x8*)(smem + ((qrow*4096 + tb) ^ SWZ(qrow)));
        s16x8 w1 = *(const s16x8*)(smem + ((qrow*4096 + tb + 64) ^ SWZ(qrow)));
        __builtin_amdgcn_s_setprio(1);
        pA = mfma16(Va0, w0, pA);
        pB = mfma16(Va1, w1, pB);
        __builtin_amdgcn_s_setprio(0);
        if (kt + 2 < 32){
          Va0 = *(const s16x8*)(vp + (kt+2)*64);
          Va1 = *(const s16x8*)(vp + (kt+2)*64 + 32);
        }
      }
      {
        int tb = ((kt+1)*64 + (l >> 4)*8)*2;
        s16x8 w0 = *(const s16x8*)(smem + ((qrow*4096 + tb) ^ SWZ(qrow)));
        s16x8 w1 = *(const s16x8*)(smem + ((qrow*4096 + tb + 64) ^ SWZ(qrow)));
        __builtin_amdgcn_s_setprio(1);
        pA = mfma16(Vb0, w0, pA);
        pB = mfma16(Vb1, w1, pB);
        __builtin_amdgcn_s_setprio(0);
        if (kt + 3 < 32){
          Vb0 = *(const s16x8*)(vp + (kt+3)*64);
          Vb1 = *(const s16x8*)(vp + (kt+3)*64 + 32);
        }
      }
    }
  }
  f32x4 pacc = pA + pB;
  // epilogue: scale by zinv, store bf16 [B][S][H*64]
  {
    float zi = zlds[qrow];
    int tok = qt*16 + qrow;
    int b = bh >> 4, h = bh & 15;
    int d0 = w*16 + (l >> 4)*4;
    u32t o0 = pk_bf16(pacc[0]*zi, pacc[1]*zi);
    u32t o1 = pk_bf16(pacc[2]*zi, pacc[3]*zi);
    *(u64t*)(aout + ((size_t)(b*NS + tok))*1024 + h*64 + d0) = (u64t)o0 | ((u64t)o1 << 32);
  }
}

// ---------------- workspace layout (~95 MB; 132 MB proven available) ----------------
#define O_XHI  ((size_t)0)
#define O_XLO  (O_XHI + (size_t)NTOK*ND*2)
#define O_WQH  (O_XLO + (size_t)NTOK*ND*2)
#define O_WQL  (O_WQH + (size_t)3072*1024*2)
#define O_WOB  (O_WQL + (size_t)3072*1024*2)
#define O_QB   (O_WOB + (size_t)1024*1024*2)
#define O_KB   (O_QB  + (size_t)NBH*NS*64*2)
#define O_VT   (O_KB  + (size_t)NBH*NS*64*2)
#define O_AOUT O_XHI   /* alias: x_hi dead after QKV GEMM */
#define WS_NEED (O_VT + (size_t)NBH*NS*64*2)

#define ATTN_LDS (65536 + 64)

extern "C" void kernel_launch(void* const* d_in, const int* in_sizes, int n_in,
                              void* d_out, int out_size, void* d_ws, size_t ws_size,
                              hipStream_t stream)
{
  (void)in_sizes; (void)n_in; (void)out_size;
  const float* x    = (const float*)d_in[0];
  const float* Wqkv = (const float*)d_in[1];
  const float* bqkv = (const float*)d_in[2];
  const float* Wo   = (const float*)d_in[3];
  const float* bo   = (const float*)d_in[4];
  float* Y = (float*)d_out;
  char* ws = (char*)d_ws;
  if (ws_size < WS_NEED) return;

  u16t* xhi  = (u16t*)(ws + O_XHI);
  u16t* xlo  = (u16t*)(ws + O_XLO);
  u16t* wqh  = (u16t*)(ws + O_WQH);
  u16t* wql  = (u16t*)(ws + O_WQL);
  u16t* wob  = (u16t*)(ws + O_WOB);
  u16t* qbuf = (u16t*)(ws + O_QB);
  u16t* kbuf = (u16t*)(ws + O_KB);
  u16t* vt   = (u16t*)(ws + O_VT);
  u16t* aout = (u16t*)(ws + O_AOUT);

  hipFuncSetAttribute((const void*)attn_fused_kernel,
                      hipFuncAttributeMaxDynamicSharedMemorySize, ATTN_LDS);

  prep_kernel<<<(N1 + N2 + N3 + 255)/256, 256, 0, stream>>>(
      x, xhi, xlo, Wqkv, wqh, wql, Wo, wob);
  qkv_gemm_kernel<<<dim3(24, 64), 256, 0, stream>>>(xhi, xlo, wqh, wql, bqkv,
                                                    qbuf, kbuf, vt);
  attn_fused_kernel<<<8192, 256, ATTN_LDS, stream>>>(qbuf, kbuf, vt, aout);
  out_gemm_kernel<<<dim3(8, 64), 256, 0, stream>>>(aout, wob, bo, Y);
}

// Round 20
// 842.833 us; speedup vs baseline: 1.0334x; 1.0334x over previous
//
#include <hip/hip_runtime.h>
#include <stdint.h>

typedef unsigned short u16t;
typedef unsigned int   u32t;
typedef unsigned long long u64t;
typedef __attribute__((ext_vector_type(4))) float f32x4;
typedef __attribute__((ext_vector_type(8))) short s16x8;
typedef __attribute__((ext_vector_type(4))) u32t u32x4;

#define NB 4
#define NS 2048
#define ND 1024
#define NH 16
#define NBH 64
#define NTOK 8192
#define TOPK 204
#define KSCALE2 738.6598609351492f   /* 4 * 1024*log2(e)/8 — 4x finer keys */

__device__ __forceinline__ u16t f2bf(float f){
  u32t u = __builtin_bit_cast(u32t, f);
  u32t r = (u + 0x7FFFu + ((u >> 16) & 1u)) >> 16;
  return (u16t)r;
}
__device__ __forceinline__ float bf2f(u16t h){
  u32t u = ((u32t)h) << 16;
  return __builtin_bit_cast(float, u);
}
__device__ __forceinline__ f32x4 mfma16(s16x8 a, s16x8 b, f32x4 c){
  return __builtin_amdgcn_mfma_f32_16x16x32_bf16(a, b, c, 0, 0, 0);
}
__device__ __forceinline__ u32t pk_bf16(float a, float b){
  u32t r;
  asm volatile("v_cvt_pk_bf16_f32 %0, %1, %2" : "=v"(r) : "v"(a), "v"(b));
  return r;
}
__device__ __forceinline__ u32t mkkey(float s){
  float kf = fmaf(s, KSCALE2, 32768.5f);  // +0.5: truncation = round-half-up (monotone)
  kf = fminf(fmaxf(kf, 0.0f), 65535.0f);  // |s_dot| <= 44.4 (11 sigma) before clamp
  return (u32t)kf;
}
__device__ __forceinline__ float exp2_fast(float x){
#if __has_builtin(__builtin_amdgcn_exp2f)
  return __builtin_amdgcn_exp2f(x);
#else
  return exp2f(x);
#endif
}

#define SWZ(r) (((r) & 7) << 4)

// ---------------- fused prep: split x, split Wqkv, cvt Wo (range-dispatched) ----------------
#define N1 (NTOK*ND/4)
#define N2 (3072*1024/4)
#define N3 (1024*1024/4)
__global__ __launch_bounds__(256) void prep_kernel(
    const float* __restrict__ x,    u16t* __restrict__ xhi, u16t* __restrict__ xlo,
    const float* __restrict__ Wq,   u16t* __restrict__ wqh, u16t* __restrict__ wql,
    const float* __restrict__ Wo,   u16t* __restrict__ wob)
{
  int i = blockIdx.x * 256 + threadIdx.x;
  const float* src; u16t* hi; u16t* lo; int idx; int dolo;
  if (i < N1){ src = x; hi = xhi; lo = xlo; idx = i; dolo = 1; }
  else if (i < N1 + N2){ src = Wq; hi = wqh; lo = wql; idx = i - N1; dolo = 1; }
  else if (i < N1 + N2 + N3){ src = Wo; hi = wob; lo = 0; idx = i - N1 - N2; dolo = 0; }
  else return;
  float4 v = ((const float4*)src)[idx];
  float a0=v.x, a1=v.y, a2=v.z, a3=v.w;
  u16t h0=f2bf(a0), h1=f2bf(a1), h2=f2bf(a2), h3=f2bf(a3);
  ((u64t*)hi)[idx] = (u64t)h0 | ((u64t)h1<<16) | ((u64t)h2<<32) | ((u64t)h3<<48);
  if (dolo){
    u16t l0=f2bf(a0-bf2f(h0)), l1=f2bf(a1-bf2f(h1)), l2=f2bf(a2-bf2f(h2)), l3=f2bf(a3-bf2f(h3));
    ((u64t*)lo)[idx] = (u64t)l0 | ((u64t)l1<<16) | ((u64t)l2<<32) | ((u64t)l3<<48);
  }
}

// ---------------- QKV GEMM: C[8192,3072] = (xh+xl)(Wh+Wl)^T + b, split 3-pass ----------------
// f32-grade accuracy; epilogue stores q,k as SINGLE bf16 and v transposed bf16.
__global__ __launch_bounds__(256) void qkv_gemm_kernel(
    const u16t* __restrict__ Ah, const u16t* __restrict__ Al,
    const u16t* __restrict__ Bh, const u16t* __restrict__ Bl,
    const float* __restrict__ bias,
    u16t* __restrict__ qb, u16t* __restrict__ kb, u16t* __restrict__ vt)
{
  __shared__ u16t lds[4*4096];
  const int tid = threadIdx.x;
  const int l = tid & 63, w = tid >> 6;
  const int wr = w >> 1, wc = w & 1;
  const int mt = blockIdx.y, nt = blockIdx.x;
  f32x4 acc[4][4] = {};
  for (int ks = 0; ks < 32; ++ks){
    __syncthreads();
    #pragma unroll
    for (int p = 0; p < 4; ++p){
      const u16t* src = (p==0) ? Ah : (p==1) ? Al : (p==2) ? Bh : Bl;
      int rb = ((p < 2) ? mt : nt) * 128;
      #pragma unroll
      for (int ii = 0; ii < 2; ++ii){
        int c = tid + ii*256;
        int row = c >> 2, kc = c & 3;
        s16x8 v = *(const s16x8*)(src + (size_t)(rb + row)*1024 + ks*32 + kc*8);
        *(s16x8*)((char*)lds + p*8192 + ((row*64 + kc*16) ^ SWZ(row))) = v;
      }
    }
    __syncthreads();
    s16x8 afh[4], afl[4], bfh[4], bfl[4];
    const int kbs = (l >> 4) * 16;
    #pragma unroll
    for (int i = 0; i < 4; ++i){
      int row = wr*64 + i*16 + (l & 15);
      int off = (row*64 + kbs) ^ SWZ(row);
      afh[i] = *(const s16x8*)((char*)lds + off);
      afl[i] = *(const s16x8*)((char*)lds + 8192 + off);
    }
    #pragma unroll
    for (int j = 0; j < 4; ++j){
      int row = wc*64 + j*16 + (l & 15);
      int off = (row*64 + kbs) ^ SWZ(row);
      bfh[j] = *(const s16x8*)((char*)lds + 16384 + off);
      bfl[j] = *(const s16x8*)((char*)lds + 24576 + off);
    }
    #pragma unroll
    for (int i = 0; i < 4; ++i)
      #pragma unroll
      for (int j = 0; j < 4; ++j){
        acc[i][j] = mfma16(afh[i], bfh[j], acc[i][j]);
        acc[i][j] = mfma16(afh[i], bfl[j], acc[i][j]);
        acc[i][j] = mfma16(afl[i], bfh[j], acc[i][j]);
      }
  }
  #pragma unroll
  for (int j = 0; j < 4; ++j){
    int col = nt*128 + wc*64 + j*16 + (l & 15);
    float bv = bias[col];
    #pragma unroll
    for (int i = 0; i < 4; ++i){
      int tok0 = mt*128 + wr*64 + i*16 + (l >> 4)*4;
      int b = tok0 >> 11;
      int s0 = tok0 & 2047;
      if (col < 1024){
        int h = col >> 6, d = col & 63;
        u16t* dst = qb + ((size_t)(b*NH + h)*NS + s0)*64 + d;
        #pragma unroll
        for (int r = 0; r < 4; ++r) dst[(size_t)r*64] = f2bf(acc[i][j][r] + bv);
      } else if (col < 2048){
        int ch = col - 1024; int h = ch >> 6, d = ch & 63;
        u16t* dst = kb + ((size_t)(b*NH + h)*NS + s0)*64 + d;
        #pragma unroll
        for (int r = 0; r < 4; ++r) dst[(size_t)r*64] = f2bf(acc[i][j][r] + bv);
      } else {
        int ch = col - 2048; int h = ch >> 6, d = ch & 63;
        u32t p0 = (u32t)f2bf(acc[i][j][0] + bv) | ((u32t)f2bf(acc[i][j][1] + bv) << 16);
        u32t p1 = (u32t)f2bf(acc[i][j][2] + bv) | ((u32t)f2bf(acc[i][j][3] + bv) << 16);
        u64t pk = (u64t)p0 | ((u64t)p1 << 32);
        *(u64t*)(vt + ((size_t)(b*NH + h)*64 + d)*NS + s0) = pk; // 4 consecutive s packed
      }
    }
  }
}

// ---------------- out GEMM: Y[8192,1024] = A(bf16) @ Wo^T(bf16) + bo, f32 out ----------------
__global__ __launch_bounds__(256) void out_gemm_kernel(
    const u16t* __restrict__ A, const u16t* __restrict__ Bt,
    const float* __restrict__ bias, float* __restrict__ Y)
{
  __shared__ u16t lds[2*4096];
  const int tid = threadIdx.x;
  const int l = tid & 63, w = tid >> 6;
  const int wr = w >> 1, wc = w & 1;
  const int mt = blockIdx.y, nt = blockIdx.x;
  f32x4 acc[4][4] = {};
  for (int ks = 0; ks < 32; ++ks){
    __syncthreads();
    #pragma unroll
    for (int p = 0; p < 2; ++p){
      const u16t* src = p ? Bt : A;
      int rb = (p ? nt : mt) * 128;
      #pragma unroll
      for (int ii = 0; ii < 2; ++ii){
        int c = tid + ii*256;
        int row = c >> 2, kc = c & 3;
        s16x8 v = *(const s16x8*)(src + (size_t)(rb + row)*1024 + ks*32 + kc*8);
        *(s16x8*)((char*)lds + p*8192 + ((row*64 + kc*16) ^ SWZ(row))) = v;
      }
    }
    __syncthreads();
    s16x8 af[4], bf[4];
    const int kbs = (l >> 4) * 16;
    #pragma unroll
    for (int i = 0; i < 4; ++i){
      int row = wr*64 + i*16 + (l & 15);
      af[i] = *(const s16x8*)((char*)lds + ((row*64 + kbs) ^ SWZ(row)));
    }
    #pragma unroll
    for (int j = 0; j < 4; ++j){
      int row = wc*64 + j*16 + (l & 15);
      bf[j] = *(const s16x8*)((char*)lds + 8192 + ((row*64 + kbs) ^ SWZ(row)));
    }
    #pragma unroll
    for (int i = 0; i < 4; ++i)
      #pragma unroll
      for (int j = 0; j < 4; ++j)
        acc[i][j] = mfma16(af[i], bf[j], acc[i][j]);
  }
  #pragma unroll
  for (int j = 0; j < 4; ++j){
    int col = nt*128 + wc*64 + j*16 + (l & 15);
    float bv = bias[col];
    #pragma unroll
    for (int i = 0; i < 4; ++i){
      int tok0 = mt*128 + wr*64 + i*16 + (l >> 4)*4;
      float* dst = Y + (size_t)tok0*1024 + col;
      #pragma unroll
      for (int r = 0; r < 4; ++r) dst[(size_t)r*1024] = acc[i][j][r] + bv;
    }
  }
}

// ---------------- fused sparse attention: 1 WG = (bh, 16 q-rows), 2 blocks/CU ----------------
// Dual-chain phase 2 (R16/R18-proven best): rows as 2 interleaved pairs — two independent
// bisection chains give 2x ILP on the serial probe critical path under the 256-VGPR budget.
__global__ __launch_bounds__(256, 2) void attn_fused_kernel(
    const u16t* __restrict__ qb, const u16t* __restrict__ kb,
    const u16t* __restrict__ vtg, u16t* __restrict__ aout)
{
  extern __shared__ char smem[];   // 65536 keys/weights + 64 zinv
  float* zlds = (float*)(smem + 65536);
  const int tid = threadIdx.x;
  const int l = tid & 63, w = tid >> 6;
  int lid = ((blockIdx.x & 7) << 10) | (blockIdx.x >> 3); // XCD-chunked swizzle (8192%8==0)
  const int bh = lid >> 7, qt = lid & 127;
  const int qrow = l & 15;
  const size_t kbase = (size_t)bh*NS*64 + (l >> 4)*8;

  // Phase 0: Q fragments (B operand): row = qrow, d-slice = c*32 + (l>>4)*8
  s16x8 qh[2];
  {
    const u16t* qp = qb + ((size_t)bh*NS + qt*16 + qrow)*64 + (l >> 4)*8;
    qh[0] = *(const s16x8*)(qp);
    qh[1] = *(const s16x8*)(qp + 32);
  }

  // Phase 1: keys. Wave w handles toks g*64 + w*16 .. +15, g = 0..31; depth-2 prefetch.
  {
    s16x8 Ah0, Ah1, Bh0, Bh1;
    {
      size_t a = kbase + (size_t)(w*16 + qrow)*64;
      Ah0 = *(const s16x8*)(kb + a);  Ah1 = *(const s16x8*)(kb + a + 32);
      size_t b = kbase + (size_t)(64 + w*16 + qrow)*64;
      Bh0 = *(const s16x8*)(kb + b);  Bh1 = *(const s16x8*)(kb + b + 32);
    }
    #pragma unroll 1
    for (int g = 0; g < 32; g += 2){
      // even iter: consume A (g), refill A with g+2
      {
        __builtin_amdgcn_s_setprio(1);
        f32x4 aA = {}, aB = {};
        aA = mfma16(Ah0, qh[0], aA);
        aB = mfma16(Ah1, qh[1], aB);
        __builtin_amdgcn_s_setprio(0);
        if (g + 2 < 32){
          size_t a = kbase + (size_t)((g+2)*64 + w*16 + qrow)*64;
          Ah0 = *(const s16x8*)(kb + a);  Ah1 = *(const s16x8*)(kb + a + 32);
        }
        f32x4 acc = aA + aB;
        int t0 = g*64 + w*16 + (l >> 4)*4;
        u32t k0 = mkkey(acc[0]), k1 = mkkey(acc[1]);
        u32t k2 = mkkey(acc[2]), k3 = mkkey(acc[3]);
        u64t pk = (u64t)(k0 | (k1 << 16)) | ((u64t)(k2 | (k3 << 16)) << 32);
        *(u64t*)(smem + ((qrow*4096 + t0*2) ^ SWZ(qrow))) = pk;
      }
      // odd iter: consume B (g+1), refill B with g+3
      {
        __builtin_amdgcn_s_setprio(1);
        f32x4 aA = {}, aB = {};
        aA = mfma16(Bh0, qh[0], aA);
        aB = mfma16(Bh1, qh[1], aB);
        __builtin_amdgcn_s_setprio(0);
        if (g + 3 < 32){
          size_t b = kbase + (size_t)((g+3)*64 + w*16 + qrow)*64;
          Bh0 = *(const s16x8*)(kb + b);  Bh1 = *(const s16x8*)(kb + b + 32);
        }
        f32x4 acc = aA + aB;
        int t0 = (g+1)*64 + w*16 + (l >> 4)*4;
        u32t k0 = mkkey(acc[0]), k1 = mkkey(acc[1]);
        u32t k2 = mkkey(acc[2]), k3 = mkkey(acc[3]);
        u64t pk = (u64t)(k0 | (k1 << 16)) | ((u64t)(k2 | (k3 << 16)) << 32);
        *(u64t*)(smem + ((qrow*4096 + t0*2) ^ SWZ(qrow))) = pk;
      }
    }
  }
  __syncthreads();

  // Phase 2: rows as 2 interleaved pairs; dual 16-probe ballot bisection; weights + zinv
  #pragma unroll 1
  for (int rp = 0; rp < 2; ++rp){
    const int rowA = w*4 + rp*2, rowB = rowA + 1;
    const int rbA = rowA*4096, rsA = SWZ(rowA);
    const int rbB = rowB*4096, rsB = SWZ(rowB);
    u32t ka[32], kc[32];
    #pragma unroll
    for (int i = 0; i < 4; ++i){
      u32x4 va = *(const u32x4*)(smem + ((rbA + i*1024 + l*16) ^ rsA));
      u32x4 vb = *(const u32x4*)(smem + ((rbB + i*1024 + l*16) ^ rsB));
      #pragma unroll
      for (int j = 0; j < 4; ++j){
        ka[(i*4+j)*2]     = va[j] & 0xFFFFu;  ka[(i*4+j)*2 + 1] = va[j] >> 16;
        kc[(i*4+j)*2]     = vb[j] & 0xFFFFu;  kc[(i*4+j)*2 + 1] = vb[j] >> 16;
      }
    }
    // dual 16-probe ballot bisection on [0, 65535] (independent chains, interleaved)
    u32t loA = 0u, hiA = 65535u, loB = 0u, hiB = 65535u;
    #pragma unroll 1
    for (int it = 0; it < 16; ++it){
      u32t midA = (loA + hiA + 1u) >> 1;
      u32t midB = (loB + hiB + 1u) >> 1;
      u32t cA = 0, cB = 0;
      #pragma unroll
      for (int i = 0; i < 32; ++i){
        cA += (u32t)__popcll(__ballot(ka[i] >= midA));
        cB += (u32t)__popcll(__ballot(kc[i] >= midB));
      }
      if (cA >= (u32t)TOPK) loA = midA; else hiA = midA - 1u;
      if (cB >= (u32t)TOPK) loB = midB; else hiB = midB - 1u;
    }
    const u32t kbtA = loA, kbtB = loB;

    // weights: kept -> 2^(k/4096 - 8); masked -> 1.0; UNNORMALIZED; zinv -> LDS.
    float zsA = 0.0f, zsB = 0.0f;
    #pragma unroll
    for (int i = 0; i < 4; ++i){
      u32x4 oa, ob;
      #pragma unroll
      for (int j = 0; j < 4; ++j){
        int e = (i*4+j)*2;
        float eA0 = exp2_fast(fmaf((float)ka[e],   2.44140625e-4f, -8.0f));
        float eA1 = exp2_fast(fmaf((float)ka[e+1], 2.44140625e-4f, -8.0f));
        float eB0 = exp2_fast(fmaf((float)kc[e],   2.44140625e-4f, -8.0f));
        float eB1 = exp2_fast(fmaf((float)kc[e+1], 2.44140625e-4f, -8.0f));
        float wA0 = (ka[e]   >= kbtA) ? eA0 : 1.0f;
        float wA1 = (ka[e+1] >= kbtA) ? eA1 : 1.0f;
        float wB0 = (kc[e]   >= kbtB) ? eB0 : 1.0f;
        float wB1 = (kc[e+1] >= kbtB) ? eB1 : 1.0f;
        zsA += wA0 + wA1;
        zsB += wB0 + wB1;
        oa[j] = pk_bf16(wA0, wA1);
        ob[j] = pk_bf16(wB0, wB1);
      }
      *(u32x4*)(smem + ((rbA + i*1024 + l*16) ^ rsA)) = oa;
      *(u32x4*)(smem + ((rbB + i*1024 + l*16) ^ rsB)) = ob;
    }
    #pragma unroll
    for (int o = 32; o; o >>= 1){
      zsA += __shfl_xor(zsA, o);
      zsB += __shfl_xor(zsB, o);
    }
    if (l == 0){
      zlds[rowA] = 1.0f / (zsA + 1e-9f);
      zlds[rowB] = 1.0f / (zsB + 1e-9f);
    }
  }
  __syncthreads();

  // Phase 3: PV via mfma(V^T, W): C[d][qrow]. Wave w owns d-block w*16..+15; depth-2 prefetch.
  f32x4 pA = {}, pB = {};
  {
    const u16t* vp = vtg + ((size_t)bh*64 + w*16 + qrow)*NS + (l >> 4)*8;
    s16x8 Va0 = *(const s16x8*)(vp);        s16x8 Va1 = *(const s16x8*)(vp + 32);
    s16x8 Vb0 = *(const s16x8*)(vp + 64);   s16x8 Vb1 = *(const s16x8*)(vp + 96);
    #pragma unroll 1
    for (int kt = 0; kt < 32; kt += 2){
      {
        int tb = (kt*64 + (l >> 4)*8)*2;
        s16x8 w0 = *(const s16x8*)(smem + ((qrow*4096 + tb) ^ SWZ(qrow)));
        s16x8 w1 = *(const s16x8*)(smem + ((qrow*4096 + tb + 64) ^ SWZ(qrow)));
        __builtin_amdgcn_s_setprio(1);
        pA = mfma16(Va0, w0, pA);
        pB = mfma16(Va1, w1, pB);
        __builtin_amdgcn_s_setprio(0);
        if (kt + 2 < 32){
          Va0 = *(const s16x8*)(vp + (kt+2)*64);
          Va1 = *(const s16x8*)(vp + (kt+2)*64 + 32);
        }
      }
      {
        int tb = ((kt+1)*64 + (l >> 4)*8)*2;
        s16x8 w0 = *(const s16x8*)(smem + ((qrow*4096 + tb) ^ SWZ(qrow)));
        s16x8 w1 = *(const s16x8*)(smem + ((qrow*4096 + tb + 64) ^ SWZ(qrow)));
        __builtin_amdgcn_s_setprio(1);
        pA = mfma16(Vb0, w0, pA);
        pB = mfma16(Vb1, w1, pB);
        __builtin_amdgcn_s_setprio(0);
        if (kt + 3 < 32){
          Vb0 = *(const s16x8*)(vp + (kt+3)*64);
          Vb1 = *(const s16x8*)(vp + (kt+3)*64 + 32);
        }
      }
    }
  }
  f32x4 pacc = pA + pB;
  // epilogue: scale by zinv, store bf16 [B][S][H*64]
  {
    float zi = zlds[qrow];
    int tok = qt*16 + qrow;
    int b = bh >> 4, h = bh & 15;
    int d0 = w*16 + (l >> 4)*4;
    u32t o0 = pk_bf16(pacc[0]*zi, pacc[1]*zi);
    u32t o1 = pk_bf16(pacc[2]*zi, pacc[3]*zi);
    *(u64t*)(aout + ((size_t)(b*NS + tok))*1024 + h*64 + d0) = (u64t)o0 | ((u64t)o1 << 32);
  }
}

// ---------------- workspace layout (~95 MB; 132 MB proven available) ----------------
#define O_XHI  ((size_t)0)
#define O_XLO  (O_XHI + (size_t)NTOK*ND*2)
#define O_WQH  (O_XLO + (size_t)NTOK*ND*2)
#define O_WQL  (O_WQH + (size_t)3072*1024*2)
#define O_WOB  (O_WQL + (size_t)3072*1024*2)
#define O_QB   (O_WOB + (size_t)1024*1024*2)
#define O_KB   (O_QB  + (size_t)NBH*NS*64*2)
#define O_VT   (O_KB  + (size_t)NBH*NS*64*2)
#define O_AOUT O_XHI   /* alias: x_hi dead after QKV GEMM */
#define WS_NEED (O_VT + (size_t)NBH*NS*64*2)

#define ATTN_LDS (65536 + 64)

extern "C" void kernel_launch(void* const* d_in, const int* in_sizes, int n_in,
                              void* d_out, int out_size, void* d_ws, size_t ws_size,
                              hipStream_t stream)
{
  (void)in_sizes; (void)n_in; (void)out_size;
  const float* x    = (const float*)d_in[0];
  const float* Wqkv = (const float*)d_in[1];
  const float* bqkv = (const float*)d_in[2];
  const float* Wo   = (const float*)d_in[3];
  const float* bo   = (const float*)d_in[4];
  float* Y = (float*)d_out;
  char* ws = (char*)d_ws;
  if (ws_size < WS_NEED) return;

  u16t* xhi  = (u16t*)(ws + O_XHI);
  u16t* xlo  = (u16t*)(ws + O_XLO);
  u16t* wqh  = (u16t*)(ws + O_WQH);
  u16t* wql  = (u16t*)(ws + O_WQL);
  u16t* wob  = (u16t*)(ws + O_WOB);
  u16t* qbuf = (u16t*)(ws + O_QB);
  u16t* kbuf = (u16t*)(ws + O_KB);
  u16t* vt   = (u16t*)(ws + O_VT);
  u16t* aout = (u16t*)(ws + O_AOUT);

  hipFuncSetAttribute((const void*)attn_fused_kernel,
                      hipFuncAttributeMaxDynamicSharedMemorySize, ATTN_LDS);

  prep_kernel<<<(N1 + N2 + N3 + 255)/256, 256, 0, stream>>>(
      x, xhi, xlo, Wqkv, wqh, wql, Wo, wob);
  qkv_gemm_kernel<<<dim3(24, 64), 256, 0, stream>>>(xhi, xlo, wqh, wql, bqkv,
                                                    qbuf, kbuf, vt);
  attn_fused_kernel<<<8192, 256, ATTN_LDS, stream>>>(qbuf, kbuf, vt, aout);
  out_gemm_kernel<<<dim3(8, 64), 256, 0, stream>>>(aout, wob, bo, Y);
}

// Round 21
// 695.417 us; speedup vs baseline: 1.2525x; 1.2120x over previous
//
#include <hip/hip_runtime.h>
#include <stdint.h>

typedef unsigned short u16t;
typedef unsigned int   u32t;
typedef unsigned long long u64t;
typedef __attribute__((ext_vector_type(4))) float f32x4;
typedef __attribute__((ext_vector_type(8))) short s16x8;
typedef __attribute__((ext_vector_type(4))) u32t u32x4;

#define NB 4
#define NS 2048
#define ND 1024
#define NH 16
#define NBH 64
#define NTOK 8192
#define TOPK 204
#define KSCALE2 738.6598609351492f   /* 4 * 1024*log2(e)/8 — 4x finer keys */

__device__ __forceinline__ u16t f2bf(float f){
  u32t u = __builtin_bit_cast(u32t, f);
  u32t r = (u + 0x7FFFu + ((u >> 16) & 1u)) >> 16;
  return (u16t)r;
}
__device__ __forceinline__ float bf2f(u16t h){
  u32t u = ((u32t)h) << 16;
  return __builtin_bit_cast(float, u);
}
__device__ __forceinline__ f32x4 mfma16(s16x8 a, s16x8 b, f32x4 c){
  return __builtin_amdgcn_mfma_f32_16x16x32_bf16(a, b, c, 0, 0, 0);
}
__device__ __forceinline__ u32t pk_bf16(float a, float b){
  u32t r;
  asm volatile("v_cvt_pk_bf16_f32 %0, %1, %2" : "=v"(r) : "v"(a), "v"(b));
  return r;
}
__device__ __forceinline__ u32t mkkey(float s){
  float kf = fmaf(s, KSCALE2, 32768.5f);  // +0.5: truncation = round-half-up (monotone)
  kf = fminf(fmaxf(kf, 0.0f), 65535.0f);  // |s_dot| <= 44.4 (11 sigma) before clamp
  return (u32t)kf;
}
__device__ __forceinline__ float exp2_fast(float x){
#if __has_builtin(__builtin_amdgcn_exp2f)
  return __builtin_amdgcn_exp2f(x);
#else
  return exp2f(x);
#endif
}

#define SWZ(r) (((r) & 7) << 4)

// ---------------- fused prep: split x, split Wqkv, cvt Wo (range-dispatched) ----------------
#define N1 (NTOK*ND/4)
#define N2 (3072*1024/4)
#define N3 (1024*1024/4)
__global__ __launch_bounds__(256) void prep_kernel(
    const float* __restrict__ x,    u16t* __restrict__ xhi, u16t* __restrict__ xlo,
    const float* __restrict__ Wq,   u16t* __restrict__ wqh, u16t* __restrict__ wql,
    const float* __restrict__ Wo,   u16t* __restrict__ wob)
{
  int i = blockIdx.x * 256 + threadIdx.x;
  const float* src; u16t* hi; u16t* lo; int idx; int dolo;
  if (i < N1){ src = x; hi = xhi; lo = xlo; idx = i; dolo = 1; }
  else if (i < N1 + N2){ src = Wq; hi = wqh; lo = wql; idx = i - N1; dolo = 1; }
  else if (i < N1 + N2 + N3){ src = Wo; hi = wob; lo = 0; idx = i - N1 - N2; dolo = 0; }
  else return;
  float4 v = ((const float4*)src)[idx];
  float a0=v.x, a1=v.y, a2=v.z, a3=v.w;
  u16t h0=f2bf(a0), h1=f2bf(a1), h2=f2bf(a2), h3=f2bf(a3);
  ((u64t*)hi)[idx] = (u64t)h0 | ((u64t)h1<<16) | ((u64t)h2<<32) | ((u64t)h3<<48);
  if (dolo){
    u16t l0=f2bf(a0-bf2f(h0)), l1=f2bf(a1-bf2f(h1)), l2=f2bf(a2-bf2f(h2)), l3=f2bf(a3-bf2f(h3));
    ((u64t*)lo)[idx] = (u64t)l0 | ((u64t)l1<<16) | ((u64t)l2<<32) | ((u64t)l3<<48);
  }
}

// ---------------- QKV GEMM: C[8192,3072] = (xh+xl)(Wh+Wl)^T + b, split 3-pass ----------------
// f32-grade accuracy; epilogue stores q,k as SINGLE bf16 and v transposed bf16.
__global__ __launch_bounds__(256) void qkv_gemm_kernel(
    const u16t* __restrict__ Ah, const u16t* __restrict__ Al,
    const u16t* __restrict__ Bh, const u16t* __restrict__ Bl,
    const float* __restrict__ bias,
    u16t* __restrict__ qb, u16t* __restrict__ kb, u16t* __restrict__ vt)
{
  __shared__ u16t lds[4*4096];
  const int tid = threadIdx.x;
  const int l = tid & 63, w = tid >> 6;
  const int wr = w >> 1, wc = w & 1;
  const int mt = blockIdx.y, nt = blockIdx.x;
  f32x4 acc[4][4] = {};
  for (int ks = 0; ks < 32; ++ks){
    __syncthreads();
    #pragma unroll
    for (int p = 0; p < 4; ++p){
      const u16t* src = (p==0) ? Ah : (p==1) ? Al : (p==2) ? Bh : Bl;
      int rb = ((p < 2) ? mt : nt) * 128;
      #pragma unroll
      for (int ii = 0; ii < 2; ++ii){
        int c = tid + ii*256;
        int row = c >> 2, kc = c & 3;
        s16x8 v = *(const s16x8*)(src + (size_t)(rb + row)*1024 + ks*32 + kc*8);
        *(s16x8*)((char*)lds + p*8192 + ((row*64 + kc*16) ^ SWZ(row))) = v;
      }
    }
    __syncthreads();
    s16x8 afh[4], afl[4], bfh[4], bfl[4];
    const int kbs = (l >> 4) * 16;
    #pragma unroll
    for (int i = 0; i < 4; ++i){
      int row = wr*64 + i*16 + (l & 15);
      int off = (row*64 + kbs) ^ SWZ(row);
      afh[i] = *(const s16x8*)((char*)lds + off);
      afl[i] = *(const s16x8*)((char*)lds + 8192 + off);
    }
    #pragma unroll
    for (int j = 0; j < 4; ++j){
      int row = wc*64 + j*16 + (l & 15);
      int off = (row*64 + kbs) ^ SWZ(row);
      bfh[j] = *(const s16x8*)((char*)lds + 16384 + off);
      bfl[j] = *(const s16x8*)((char*)lds + 24576 + off);
    }
    #pragma unroll
    for (int i = 0; i < 4; ++i)
      #pragma unroll
      for (int j = 0; j < 4; ++j){
        acc[i][j] = mfma16(afh[i], bfh[j], acc[i][j]);
        acc[i][j] = mfma16(afh[i], bfl[j], acc[i][j]);
        acc[i][j] = mfma16(afl[i], bfh[j], acc[i][j]);
      }
  }
  #pragma unroll
  for (int j = 0; j < 4; ++j){
    int col = nt*128 + wc*64 + j*16 + (l & 15);
    float bv = bias[col];
    #pragma unroll
    for (int i = 0; i < 4; ++i){
      int tok0 = mt*128 + wr*64 + i*16 + (l >> 4)*4;
      int b = tok0 >> 11;
      int s0 = tok0 & 2047;
      if (col < 1024){
        int h = col >> 6, d = col & 63;
        u16t* dst = qb + ((size_t)(b*NH + h)*NS + s0)*64 + d;
        #pragma unroll
        for (int r = 0; r < 4; ++r) dst[(size_t)r*64] = f2bf(acc[i][j][r] + bv);
      } else if (col < 2048){
        int ch = col - 1024; int h = ch >> 6, d = ch & 63;
        u16t* dst = kb + ((size_t)(b*NH + h)*NS + s0)*64 + d;
        #pragma unroll
        for (int r = 0; r < 4; ++r) dst[(size_t)r*64] = f2bf(acc[i][j][r] + bv);
      } else {
        int ch = col - 2048; int h = ch >> 6, d = ch & 63;
        u32t p0 = (u32t)f2bf(acc[i][j][0] + bv) | ((u32t)f2bf(acc[i][j][1] + bv) << 16);
        u32t p1 = (u32t)f2bf(acc[i][j][2] + bv) | ((u32t)f2bf(acc[i][j][3] + bv) << 16);
        u64t pk = (u64t)p0 | ((u64t)p1 << 32);
        *(u64t*)(vt + ((size_t)(b*NH + h)*64 + d)*NS + s0) = pk; // 4 consecutive s packed
      }
    }
  }
}

// ---------------- out GEMM: Y[8192,1024] = A(bf16) @ Wo^T(bf16) + bo, f32 out ----------------
__global__ __launch_bounds__(256) void out_gemm_kernel(
    const u16t* __restrict__ A, const u16t* __restrict__ Bt,
    const float* __restrict__ bias, float* __restrict__ Y)
{
  __shared__ u16t lds[2*4096];
  const int tid = threadIdx.x;
  const int l = tid & 63, w = tid >> 6;
  const int wr = w >> 1, wc = w & 1;
  const int mt = blockIdx.y, nt = blockIdx.x;
  f32x4 acc[4][4] = {};
  for (int ks = 0; ks < 32; ++ks){
    __syncthreads();
    #pragma unroll
    for (int p = 0; p < 2; ++p){
      const u16t* src = p ? Bt : A;
      int rb = (p ? nt : mt) * 128;
      #pragma unroll
      for (int ii = 0; ii < 2; ++ii){
        int c = tid + ii*256;
        int row = c >> 2, kc = c & 3;
        s16x8 v = *(const s16x8*)(src + (size_t)(rb + row)*1024 + ks*32 + kc*8);
        *(s16x8*)((char*)lds + p*8192 + ((row*64 + kc*16) ^ SWZ(row))) = v;
      }
    }
    __syncthreads();
    s16x8 af[4], bf[4];
    const int kbs = (l >> 4) * 16;
    #pragma unroll
    for (int i = 0; i < 4; ++i){
      int row = wr*64 + i*16 + (l & 15);
      af[i] = *(const s16x8*)((char*)lds + ((row*64 + kbs) ^ SWZ(row)));
    }
    #pragma unroll
    for (int j = 0; j < 4; ++j){
      int row = wc*64 + j*16 + (l & 15);
      bf[j] = *(const s16x8*)((char*)lds + 8192 + ((row*64 + kbs) ^ SWZ(row)));
    }
    #pragma unroll
    for (int i = 0; i < 4; ++i)
      #pragma unroll
      for (int j = 0; j < 4; ++j)
        acc[i][j] = mfma16(af[i], bf[j], acc[i][j]);
  }
  #pragma unroll
  for (int j = 0; j < 4; ++j){
    int col = nt*128 + wc*64 + j*16 + (l & 15);
    float bv = bias[col];
    #pragma unroll
    for (int i = 0; i < 4; ++i){
      int tok0 = mt*128 + wr*64 + i*16 + (l >> 4)*4;
      float* dst = Y + (size_t)tok0*1024 + col;
      #pragma unroll
      for (int r = 0; r < 4; ++r) dst[(size_t)r*1024] = acc[i][j][r] + bv;
    }
  }
}

// ---------------- fused sparse attention: 1 WG = (bh, 16 q-rows), 512 thr, 2 blocks/CU ----
// 8 waves (4 waves/SIMD) on phases 1-2; phase 3 + epilogue run on waves 0-3 only (R20
// code verbatim, no cross-wave reduction). Score/select/weight arithmetic bit-identical
// to R20 — only the wave->token / wave->row mapping changes.
__global__ __launch_bounds__(512, 2) void attn_fused_kernel(
    const u16t* __restrict__ qb, const u16t* __restrict__ kb,
    const u16t* __restrict__ vtg, u16t* __restrict__ aout)
{
  extern __shared__ char smem[];   // 65536 keys/weights + 64 zinv
  float* zlds = (float*)(smem + 65536);
  const int tid = threadIdx.x;
  const int l = tid & 63, w = tid >> 6;        // w = 0..7
  int lid = ((blockIdx.x & 7) << 10) | (blockIdx.x >> 3); // XCD-chunked swizzle (8192%8==0)
  const int bh = lid >> 7, qt = lid & 127;
  const int qrow = l & 15;
  const size_t kbase = (size_t)bh*NS*64 + (l >> 4)*8;

  // Phase 0: Q fragments (B operand): row = qrow, d-slice = c*32 + (l>>4)*8
  s16x8 qh[2];
  {
    const u16t* qp = qb + ((size_t)bh*NS + qt*16 + qrow)*64 + (l >> 4)*8;
    qh[0] = *(const s16x8*)(qp);
    qh[1] = *(const s16x8*)(qp + 32);
  }

  // Phase 1: keys. Wave w handles toks i*128 + w*16 .. +15, i = 0..15; depth-2 prefetch.
  {
    s16x8 Ah0, Ah1, Bh0, Bh1;
    {
      size_t a = kbase + (size_t)(w*16 + qrow)*64;
      Ah0 = *(const s16x8*)(kb + a);  Ah1 = *(const s16x8*)(kb + a + 32);
      size_t b = kbase + (size_t)(128 + w*16 + qrow)*64;
      Bh0 = *(const s16x8*)(kb + b);  Bh1 = *(const s16x8*)(kb + b + 32);
    }
    #pragma unroll 1
    for (int g = 0; g < 16; g += 2){
      // even iter: consume A (i=g), refill A with i=g+2
      {
        __builtin_amdgcn_s_setprio(1);
        f32x4 aA = {}, aB = {};
        aA = mfma16(Ah0, qh[0], aA);
        aB = mfma16(Ah1, qh[1], aB);
        __builtin_amdgcn_s_setprio(0);
        if (g + 2 < 16){
          size_t a = kbase + (size_t)((g+2)*128 + w*16 + qrow)*64;
          Ah0 = *(const s16x8*)(kb + a);  Ah1 = *(const s16x8*)(kb + a + 32);
        }
        f32x4 acc = aA + aB;
        int t0 = g*128 + w*16 + (l >> 4)*4;
        u32t k0 = mkkey(acc[0]), k1 = mkkey(acc[1]);
        u32t k2 = mkkey(acc[2]), k3 = mkkey(acc[3]);
        u64t pk = (u64t)(k0 | (k1 << 16)) | ((u64t)(k2 | (k3 << 16)) << 32);
        *(u64t*)(smem + ((qrow*4096 + t0*2) ^ SWZ(qrow))) = pk;
      }
      // odd iter: consume B (i=g+1), refill B with i=g+3
      {
        __builtin_amdgcn_s_setprio(1);
        f32x4 aA = {}, aB = {};
        aA = mfma16(Bh0, qh[0], aA);
        aB = mfma16(Bh1, qh[1], aB);
        __builtin_amdgcn_s_setprio(0);
        if (g + 3 < 16){
          size_t b = kbase + (size_t)((g+3)*128 + w*16 + qrow)*64;
          Bh0 = *(const s16x8*)(kb + b);  Bh1 = *(const s16x8*)(kb + b + 32);
        }
        f32x4 acc = aA + aB;
        int t0 = (g+1)*128 + w*16 + (l >> 4)*4;
        u32t k0 = mkkey(acc[0]), k1 = mkkey(acc[1]);
        u32t k2 = mkkey(acc[2]), k3 = mkkey(acc[3]);
        u64t pk = (u64t)(k0 | (k1 << 16)) | ((u64t)(k2 | (k3 << 16)) << 32);
        *(u64t*)(smem + ((qrow*4096 + t0*2) ^ SWZ(qrow))) = pk;
      }
    }
  }
  __syncthreads();

  // Phase 2: wave w owns rows {w*2, w*2+1}; one dual 16-probe ballot bisection pass
  {
    const int rowA = w*2, rowB = rowA + 1;
    const int rbA = rowA*4096, rsA = SWZ(rowA);
    const int rbB = rowB*4096, rsB = SWZ(rowB);
    u32t ka[32], kc[32];
    #pragma unroll
    for (int i = 0; i < 4; ++i){
      u32x4 va = *(const u32x4*)(smem + ((rbA + i*1024 + l*16) ^ rsA));
      u32x4 vb = *(const u32x4*)(smem + ((rbB + i*1024 + l*16) ^ rsB));
      #pragma unroll
      for (int j = 0; j < 4; ++j){
        ka[(i*4+j)*2]     = va[j] & 0xFFFFu;  ka[(i*4+j)*2 + 1] = va[j] >> 16;
        kc[(i*4+j)*2]     = vb[j] & 0xFFFFu;  kc[(i*4+j)*2 + 1] = vb[j] >> 16;
      }
    }
    // dual 16-probe ballot bisection on [0, 65535] (independent chains, interleaved)
    u32t loA = 0u, hiA = 65535u, loB = 0u, hiB = 65535u;
    #pragma unroll 1
    for (int it = 0; it < 16; ++it){
      u32t midA = (loA + hiA + 1u) >> 1;
      u32t midB = (loB + hiB + 1u) >> 1;
      u32t cA = 0, cB = 0;
      #pragma unroll
      for (int i = 0; i < 32; ++i){
        cA += (u32t)__popcll(__ballot(ka[i] >= midA));
        cB += (u32t)__popcll(__ballot(kc[i] >= midB));
      }
      if (cA >= (u32t)TOPK) loA = midA; else hiA = midA - 1u;
      if (cB >= (u32t)TOPK) loB = midB; else hiB = midB - 1u;
    }
    const u32t kbtA = loA, kbtB = loB;

    // weights: kept -> 2^(k/4096 - 8); masked -> 1.0; UNNORMALIZED; zinv -> LDS.
    float zsA = 0.0f, zsB = 0.0f;
    #pragma unroll
    for (int i = 0; i < 4; ++i){
      u32x4 oa, ob;
      #pragma unroll
      for (int j = 0; j < 4; ++j){
        int e = (i*4+j)*2;
        float eA0 = exp2_fast(fmaf((float)ka[e],   2.44140625e-4f, -8.0f));
        float eA1 = exp2_fast(fmaf((float)ka[e+1], 2.44140625e-4f, -8.0f));
        float eB0 = exp2_fast(fmaf((float)kc[e],   2.44140625e-4f, -8.0f));
        float eB1 = exp2_fast(fmaf((float)kc[e+1], 2.44140625e-4f, -8.0f));
        float wA0 = (ka[e]   >= kbtA) ? eA0 : 1.0f;
        float wA1 = (ka[e+1] >= kbtA) ? eA1 : 1.0f;
        float wB0 = (kc[e]   >= kbtB) ? eB0 : 1.0f;
        float wB1 = (kc[e+1] >= kbtB) ? eB1 : 1.0f;
        zsA += wA0 + wA1;
        zsB += wB0 + wB1;
        oa[j] = pk_bf16(wA0, wA1);
        ob[j] = pk_bf16(wB0, wB1);
      }
      *(u32x4*)(smem + ((rbA + i*1024 + l*16) ^ rsA)) = oa;
      *(u32x4*)(smem + ((rbB + i*1024 + l*16) ^ rsB)) = ob;
    }
    #pragma unroll
    for (int o = 32; o; o >>= 1){
      zsA += __shfl_xor(zsA, o);
      zsB += __shfl_xor(zsB, o);
    }
    if (l == 0){
      zlds[rowA] = 1.0f / (zsA + 1e-9f);
      zlds[rowB] = 1.0f / (zsB + 1e-9f);
    }
  }
  __syncthreads();

  // Phase 3 + epilogue: waves 0-3 only (R20 verbatim); waves 4-7 retire early.
  if (w < 4){
    f32x4 pA = {}, pB = {};
    {
      const u16t* vp = vtg + ((size_t)bh*64 + w*16 + qrow)*NS + (l >> 4)*8;
      s16x8 Va0 = *(const s16x8*)(vp);        s16x8 Va1 = *(const s16x8*)(vp + 32);
      s16x8 Vb0 = *(const s16x8*)(vp + 64);   s16x8 Vb1 = *(const s16x8*)(vp + 96);
      #pragma unroll 1
      for (int kt = 0; kt < 32; kt += 2){
        {
          int tb = (kt*64 + (l >> 4)*8)*2;
          s16x8 w0 = *(const s16x8*)(smem + ((qrow*4096 + tb) ^ SWZ(qrow)));
          s16x8 w1 = *(const s16x8*)(smem + ((qrow*4096 + tb + 64) ^ SWZ(qrow)));
          __builtin_amdgcn_s_setprio(1);
          pA = mfma16(Va0, w0, pA);
          pB = mfma16(Va1, w1, pB);
          __builtin_amdgcn_s_setprio(0);
          if (kt + 2 < 32){
            Va0 = *(const s16x8*)(vp + (kt+2)*64);
            Va1 = *(const s16x8*)(vp + (kt+2)*64 + 32);
          }
        }
        {
          int tb = ((kt+1)*64 + (l >> 4)*8)*2;
          s16x8 w0 = *(const s16x8*)(smem + ((qrow*4096 + tb) ^ SWZ(qrow)));
          s16x8 w1 = *(const s16x8*)(smem + ((qrow*4096 + tb + 64) ^ SWZ(qrow)));
          __builtin_amdgcn_s_setprio(1);
          pA = mfma16(Vb0, w0, pA);
          pB = mfma16(Vb1, w1, pB);
          __builtin_amdgcn_s_setprio(0);
          if (kt + 3 < 32){
            Vb0 = *(const s16x8*)(vp + (kt+3)*64);
            Vb1 = *(const s16x8*)(vp + (kt+3)*64 + 32);
          }
        }
      }
    }
    f32x4 pacc = pA + pB;
    // epilogue: scale by zinv, store bf16 [B][S][H*64]
    {
      float zi = zlds[qrow];
      int tok = qt*16 + qrow;
      int b = bh >> 4, h = bh & 15;
      int d0 = w*16 + (l >> 4)*4;
      u32t o0 = pk_bf16(pacc[0]*zi, pacc[1]*zi);
      u32t o1 = pk_bf16(pacc[2]*zi, pacc[3]*zi);
      *(u64t*)(aout + ((size_t)(b*NS + tok))*1024 + h*64 + d0) = (u64t)o0 | ((u64t)o1 << 32);
    }
  }
}

// ---------------- workspace layout (~95 MB; 132 MB proven available) ----------------
#define O_XHI  ((size_t)0)
#define O_XLO  (O_XHI + (size_t)NTOK*ND*2)
#define O_WQH  (O_XLO + (size_t)NTOK*ND*2)
#define O_WQL  (O_WQH + (size_t)3072*1024*2)
#define O_WOB  (O_WQL + (size_t)3072*1024*2)
#define O_QB   (O_WOB + (size_t)1024*1024*2)
#define O_KB   (O_QB  + (size_t)NBH*NS*64*2)
#define O_VT   (O_KB  + (size_t)NBH*NS*64*2)
#define O_AOUT O_XHI   /* alias: x_hi dead after QKV GEMM */
#define WS_NEED (O_VT + (size_t)NBH*NS*64*2)

#define ATTN_LDS (65536 + 64)

extern "C" void kernel_launch(void* const* d_in, const int* in_sizes, int n_in,
                              void* d_out, int out_size, void* d_ws, size_t ws_size,
                              hipStream_t stream)
{
  (void)in_sizes; (void)n_in; (void)out_size;
  const float* x    = (const float*)d_in[0];
  const float* Wqkv = (const float*)d_in[1];
  const float* bqkv = (const float*)d_in[2];
  const float* Wo   = (const float*)d_in[3];
  const float* bo   = (const float*)d_in[4];
  float* Y = (float*)d_out;
  char* ws = (char*)d_ws;
  if (ws_size < WS_NEED) return;

  u16t* xhi  = (u16t*)(ws + O_XHI);
  u16t* xlo  = (u16t*)(ws + O_XLO);
  u16t* wqh  = (u16t*)(ws + O_WQH);
  u16t* wql  = (u16t*)(ws + O_WQL);
  u16t* wob  = (u16t*)(ws + O_WOB);
  u16t* qbuf = (u16t*)(ws + O_QB);
  u16t* kbuf = (u16t*)(ws + O_KB);
  u16t* vt   = (u16t*)(ws + O_VT);
  u16t* aout = (u16t*)(ws + O_AOUT);

  hipFuncSetAttribute((const void*)attn_fused_kernel,
                      hipFuncAttributeMaxDynamicSharedMemorySize, ATTN_LDS);

  prep_kernel<<<(N1 + N2 + N3 + 255)/256, 256, 0, stream>>>(
      x, xhi, xlo, Wqkv, wqh, wql, Wo, wob);
  qkv_gemm_kernel<<<dim3(24, 64), 256, 0, stream>>>(xhi, xlo, wqh, wql, bqkv,
                                                    qbuf, kbuf, vt);
  attn_fused_kernel<<<8192, 512, ATTN_LDS, stream>>>(qbuf, kbuf, vt, aout);
  out_gemm_kernel<<<dim3(8, 64), 256, 0, stream>>>(aout, wob, bo, Y);
}